// Round 9
// baseline (150.657 us; speedup 1.0000x reference)
//
#include <hip/hip_runtime.h>
#include <math.h>

#define NB 8192
#define ND 64
#define NL 80
#define NBLK 512

typedef __attribute__((ext_vector_type(8))) __bf16 bf16x8;
typedef __attribute__((ext_vector_type(16))) float f32x16;

// LDS layout (40960 B, phase-multiplexed)
#define LDS_AHI 0
#define LDS_ALO 16384
#define LDS_PL  32768
#define LDS_TH  34816
#define LDS_VAL 36864
#define LDS_SCR 37376
#define LDS_ANY 40448
#define LDS_WS  40452

// Grid-barrier state in module globals (not d_ws -> poison-immune).
// Generation counter: cnt returns to 0 after each use, gen increases
// monotonically (wrap harmless) -> identical behavior on every replay.
__device__ unsigned g_cnt = 0u;
__device__ unsigned g_gen = 0u;

__device__ __forceinline__ void gridbar() {
    __syncthreads();
    if (threadIdx.x == 0) {
        __threadfence();
        unsigned g = __hip_atomic_load(&g_gen, __ATOMIC_RELAXED, __HIP_MEMORY_SCOPE_AGENT);
        unsigned a = __hip_atomic_fetch_add(&g_cnt, 1u, __ATOMIC_ACQ_REL, __HIP_MEMORY_SCOPE_AGENT);
        if (a == (unsigned)(NBLK - 1)) {
            __hip_atomic_store(&g_cnt, 0u, __ATOMIC_RELAXED, __HIP_MEMORY_SCOPE_AGENT);
            __hip_atomic_fetch_add(&g_gen, 1u, __ATOMIC_RELEASE, __HIP_MEMORY_SCOPE_AGENT);
        } else {
            while (__hip_atomic_load(&g_gen, __ATOMIC_ACQUIRE, __HIP_MEMORY_SCOPE_AGENT) == g)
                __builtin_amdgcn_s_sleep(2);
        }
        __threadfence();
    }
    __syncthreads();
}

__device__ __forceinline__ unsigned bf16rne(float x) {
    unsigned u = __float_as_uint(x);
    unsigned r = u + 0x7FFFu + ((u >> 16) & 1u);
    return r >> 16;
}
__device__ __forceinline__ float bf16tof(unsigned h) {
    return __uint_as_float(h << 16);
}

__device__ __forceinline__ void split8(float4 va, float4 vb, uint4* hi, uint4* lo) {
    float f[8] = {va.x, va.y, va.z, va.w, vb.x, vb.y, vb.z, vb.w};
    unsigned h[8], l[8];
#pragma unroll
    for (int k = 0; k < 8; ++k) {
        h[k] = bf16rne(f[k]);
        l[k] = bf16rne(f[k] - bf16tof(h[k]));
    }
    *hi = make_uint4(h[0] | (h[1] << 16), h[2] | (h[3] << 16),
                     h[4] | (h[5] << 16), h[6] | (h[7] << 16));
    *lo = make_uint4(l[0] | (l[1] << 16), l[2] | (l[3] << 16),
                     l[4] | (l[5] << 16), l[6] | (l[7] << 16));
}

// Stage 128-row A(j) panel, XOR-swizzled (G4: byte ^= (row&7)<<4), fp32->bf16 on the fly.
__device__ __forceinline__ void stage_A(char* lds, const float4* __restrict__ F4,
        int j0, int tid) {
#pragma unroll
    for (int t = 0; t < 4; ++t) {
        int idx = tid + t * 256;          // 0..1023
        int row = idx >> 3, c8 = idx & 7;
        float4 v0 = F4[(size_t)(j0 + row) * 16 + c8 * 2];
        float4 v1 = F4[(size_t)(j0 + row) * 16 + c8 * 2 + 1];
        uint4 hi, lo;
        split8(v0, v1, &hi, &lo);
        int dst = row * 128 + ((c8 * 16) ^ ((row & 7) << 4));
        *(uint4*)(lds + LDS_AHI + dst) = hi;
        *(uint4*)(lds + LDS_ALO + dst) = lo;
    }
}

// 64x64 per wave: 3-split product of Fj-panel (LDS) x Fi-panel^T (global fp32).
// C layout (m74/m101): col=lane&31 (i), row=(reg&3)+8*(reg>>2)+4*(lane>>5) (j).
__device__ __forceinline__ void compute_tile(const char* lds,
        const float4* __restrict__ F4, int i0, int wr, int wc, int lane,
        f32x16 acc[2][2]) {
    const int l31 = lane & 31, lhalf = lane >> 5;
    const int swz = (l31 & 7) << 4;
    const int abase = (wr * 64 + l31) * 128;
    const size_t br0 = (size_t)(i0 + wc * 64 + l31) * 16;
    const size_t br1 = br0 + 32 * 16;
#pragma unroll
    for (int ks = 0; ks < 4; ++ks) {
        int off = (ks * 32 + lhalf * 16) ^ swz;
        int ci = ks * 2 + lhalf;
        bf16x8 a0h = *(const bf16x8*)(lds + LDS_AHI + abase + off);
        bf16x8 a1h = *(const bf16x8*)(lds + LDS_AHI + abase + 32 * 128 + off);
        bf16x8 a0l = *(const bf16x8*)(lds + LDS_ALO + abase + off);
        bf16x8 a1l = *(const bf16x8*)(lds + LDS_ALO + abase + 32 * 128 + off);
        uint4 b0hu, b0lu, b1hu, b1lu;
        split8(F4[br0 + ci * 2], F4[br0 + ci * 2 + 1], &b0hu, &b0lu);
        split8(F4[br1 + ci * 2], F4[br1 + ci * 2 + 1], &b1hu, &b1lu);
        bf16x8 b0h = __builtin_bit_cast(bf16x8, b0hu);
        bf16x8 b0l = __builtin_bit_cast(bf16x8, b0lu);
        bf16x8 b1h = __builtin_bit_cast(bf16x8, b1hu);
        bf16x8 b1l = __builtin_bit_cast(bf16x8, b1lu);
        acc[0][0] = __builtin_amdgcn_mfma_f32_32x32x16_bf16(a0h, b0h, acc[0][0], 0, 0, 0);
        acc[0][0] = __builtin_amdgcn_mfma_f32_32x32x16_bf16(a0h, b0l, acc[0][0], 0, 0, 0);
        acc[0][0] = __builtin_amdgcn_mfma_f32_32x32x16_bf16(a0l, b0h, acc[0][0], 0, 0, 0);
        acc[0][1] = __builtin_amdgcn_mfma_f32_32x32x16_bf16(a0h, b1h, acc[0][1], 0, 0, 0);
        acc[0][1] = __builtin_amdgcn_mfma_f32_32x32x16_bf16(a0h, b1l, acc[0][1], 0, 0, 0);
        acc[0][1] = __builtin_amdgcn_mfma_f32_32x32x16_bf16(a0l, b1h, acc[0][1], 0, 0, 0);
        acc[1][0] = __builtin_amdgcn_mfma_f32_32x32x16_bf16(a1h, b0h, acc[1][0], 0, 0, 0);
        acc[1][0] = __builtin_amdgcn_mfma_f32_32x32x16_bf16(a1h, b0l, acc[1][0], 0, 0, 0);
        acc[1][0] = __builtin_amdgcn_mfma_f32_32x32x16_bf16(a1l, b0h, acc[1][0], 0, 0, 0);
        acc[1][1] = __builtin_amdgcn_mfma_f32_32x32x16_bf16(a1h, b1h, acc[1][1], 0, 0, 0);
        acc[1][1] = __builtin_amdgcn_mfma_f32_32x32x16_bf16(a1h, b1l, acc[1][1], 0, 0, 0);
        acc[1][1] = __builtin_amdgcn_mfma_f32_32x32x16_bf16(a1l, b1h, acc[1][1], 0, 0, 0);
    }
}

__global__ __launch_bounds__(256, 2) void k_all(
        const float* __restrict__ F, const int* __restrict__ labels,
        ulonglong2* __restrict__ pl, unsigned* __restrict__ tneed,
        float* __restrict__ out) {
    __shared__ char lds[40960];
    const int b = blockIdx.x, t = threadIdx.x;
    const int gid = b * 256 + t;
    const int lane = t & 63;

    // ===== P0: zero flags/out; ballot-pack labels (4 rows per wave) =====
    if (gid < 64) tneed[gid] = 0u;
    if (gid == 0) out[0] = 0.f;
    {
        int w = gid >> 6;                            // 0..2047
        const int* base = labels + (size_t)w * 4 * NL;
#pragma unroll
        for (int r = 0; r < 4; ++r) {
            int v0 = base[r * NL + lane];
            int v1 = (lane < 16) ? base[r * NL + 64 + lane] : 0;
            unsigned long long lo = __ballot(v0 != 0);
            unsigned long long hi = __ballot(v1 != 0);
            if (lane == 0) { pl[w * 4 + r].x = lo; pl[w * 4 + r].y = hi; }
        }
    }
    gridbar();

    // ===== P1: label-only need flags (R7-verified config: LDS PJ, 4 rows/thr) =====
    {
        const uint4* pl4 = (const uint4*)pl;
        uint4* PJ = (uint4*)lds;
#pragma unroll 1
        for (int u = b; u < 1024; u += NBLK) {       // 2 units per block
            const int js = u & 127, rg = u >> 7;
            __syncthreads();                          // prior unit done reading PJ
            if (t < 64) PJ[t] = pl4[js * 64 + t];
            __syncthreads();
            const int r0 = rg * 1024 + t * 4;
            uint4 mi[4];
            unsigned nm[4] = {0xFFFFFFFFu, 0xFFFFFFFFu, 0xFFFFFFFFu, 0xFFFFFFFFu};
#pragma unroll
            for (int k = 0; k < 4; ++k) mi[k] = pl4[r0 + k];
#pragma unroll 4
            for (int j = 0; j < 64; ++j) {
                uint4 pj = PJ[j];
#pragma unroll
                for (int k = 0; k < 4; ++k) {
                    unsigned x = (mi[k].x & pj.x) | (mi[k].y & pj.y) | (mi[k].z & pj.z);
                    nm[k] = min(nm[k], x);
                }
            }
            bool need = false;
#pragma unroll
            for (int k = 0; k < 4; ++k) {
                bool pos = (mi[k].x | mi[k].y | mi[k].z) != 0u;
                need = need || (pos && nm[k] == 0u);
            }
            if (need) atomicOr(&tneed[r0 >> 7], 1u);
        }
    }
    gridbar();

    // ===== P2: gated sim pipeline (R7-verified body), blocks 0..63 =====
    if (b >= 64) return;
    if (tneed[b] == 0u) return;
    const float4* F4 = (const float4*)F;
    const int i0 = b * 128;
    const int wv = t >> 6;
    const int wr = wv >> 1, wc = wv & 1;
    const int l31 = lane & 31, lhalf = lane >> 5;

    ulonglong2 pi[2];
    pi[0] = pl[i0 + wc * 64 + l31];
    pi[1] = pl[i0 + wc * 64 + 32 + l31];

    // pass 1: full j-range, stats in regs
    float ssq[2] = {0.f, 0.f};
    float mnp[2] = {INFINITY, INFINITY};
    float mxn[2] = {-INFINITY, -INFINITY};
    for (int js = 0; js < 64; ++js) {
        const int j0 = js * 128;
        __syncthreads();
        stage_A(lds, F4, j0, t);
        if (t < 128) *(ulonglong2*)(lds + LDS_PL + t * 16) = pl[j0 + t];
        __syncthreads();
        f32x16 acc[2][2] = {};
        compute_tile(lds, F4, i0, wr, wc, lane, acc);
#pragma unroll
        for (int m = 0; m < 2; ++m) {
#pragma unroll
            for (int reg = 0; reg < 16; ++reg) {
                int jl = wr * 64 + m * 32 + (reg & 3) + 8 * (reg >> 2) + 4 * lhalf;
                ulonglong2 pj = *(const ulonglong2*)(lds + LDS_PL + jl * 16);
#pragma unroll
                for (int n = 0; n < 2; ++n) {
                    float s = acc[m][n][reg];
                    bool pos = (((pi[n].x & pj.x) | (pi[n].y & pj.y)) != 0ull);
                    ssq[n] += s * s;
                    mnp[n] = fminf(mnp[n], pos ? s : INFINITY);
                    mxn[n] = fmaxf(mxn[n], pos ? -INFINITY : s);
                }
            }
        }
    }
#pragma unroll
    for (int n = 0; n < 2; ++n) {
        ssq[n] += __shfl_xor(ssq[n], 32);
        mnp[n] = fminf(mnp[n], __shfl_xor(mnp[n], 32));
        mxn[n] = fmaxf(mxn[n], __shfl_xor(mxn[n], 32));
    }
    float* SC2 = (float*)(lds + LDS_SCR);
    int* ANYV = (int*)(lds + LDS_ANY);
    if (lane < 32) {
#pragma unroll
        for (int n = 0; n < 2; ++n) {
            int il = wc * 64 + n * 32 + lane;
            SC2[(wr * 128 + il) * 3 + 0] = ssq[n];
            SC2[(wr * 128 + il) * 3 + 1] = mnp[n];
            SC2[(wr * 128 + il) * 3 + 2] = mxn[n];
        }
    }
    if (t == 0) *ANYV = 0;
    __syncthreads();
    if (t < 128) {
        float s2 = SC2[t * 3] + SC2[(128 + t) * 3];
        float mp = fminf(SC2[t * 3 + 1], SC2[(128 + t) * 3 + 1]);
        float mg = fmaxf(SC2[t * 3 + 2], SC2[(128 + t) * 3 + 2]);
        float div = fmaxf(sqrtf(s2), 1e-12f);
        float inv = 1.f / div;
        float eraw = (1.0f - 1e-5f) * div;
        bool hasp = (mp < eraw);
        bool hasn = (mg > -INFINITY);
        float minpos_n = hasp ? mp * inv : INFINITY;
        float maxneg_n = hasn ? mg * inv : -INFINITY;
        float4 th;
        th.x = (minpos_n - 0.1f) * div;   // neg_sel: raw > th.x
        th.y = (maxneg_n + 0.1f) * div;   // pos_sel: raw < th.y
        th.z = eraw;                      // pos_valid: raw < th.z
        th.w = inv;
        *(float4*)(lds + LDS_TH + t * 16) = th;
        ((int*)(lds + LDS_VAL))[t] = (hasp && hasn) ? 1 : 0;
        if (hasp && hasn) *ANYV = 1;
    }
    __syncthreads();
    if (*ANYV == 0) return;

    // pass 2: mined exp sums
    float tn[2], tp[2], te[2], iv[2];
#pragma unroll
    for (int n = 0; n < 2; ++n) {
        int il = wc * 64 + n * 32 + l31;
        float4 th = *(const float4*)(lds + LDS_TH + il * 16);
        tn[n] = th.x; tp[n] = th.y; te[n] = th.z; iv[n] = th.w;
    }
    float psum[2] = {0.f, 0.f}, nsum[2] = {0.f, 0.f};
    for (int js = 0; js < 64; ++js) {
        const int j0 = js * 128;
        __syncthreads();
        stage_A(lds, F4, j0, t);
        if (t < 128) *(ulonglong2*)(lds + LDS_PL + t * 16) = pl[j0 + t];
        __syncthreads();
        f32x16 acc[2][2] = {};
        compute_tile(lds, F4, i0, wr, wc, lane, acc);
#pragma unroll
        for (int m = 0; m < 2; ++m) {
#pragma unroll
            for (int reg = 0; reg < 16; ++reg) {
                int jl = wr * 64 + m * 32 + (reg & 3) + 8 * (reg >> 2) + 4 * lhalf;
                ulonglong2 pj = *(const ulonglong2*)(lds + LDS_PL + jl * 16);
#pragma unroll
                for (int n = 0; n < 2; ++n) {
                    float s = acc[m][n][reg];
                    bool pos = (((pi[n].x & pj.x) | (pi[n].y & pj.y)) != 0ull);
                    float sn = s * iv[n];
                    bool psel = pos && (s < te[n]) && (s < tp[n]);
                    bool nsel = (!pos) && (s > tn[n]);
                    float arg = pos ? fmaf(-2.0f, sn, 0.2f) : fmaf(40.0f, sn, -4.0f);
                    float ev = __expf(arg);
                    psum[n] += psel ? ev : 0.0f;
                    nsum[n] += nsel ? ev : 0.0f;
                }
            }
        }
    }
#pragma unroll
    for (int n = 0; n < 2; ++n) {
        psum[n] += __shfl_xor(psum[n], 32);
        nsum[n] += __shfl_xor(nsum[n], 32);
    }
    __syncthreads();
    if (lane < 32) {
#pragma unroll
        for (int n = 0; n < 2; ++n) {
            int il = wc * 64 + n * 32 + lane;
            SC2[(wr * 128 + il) * 2 + 0] = psum[n];
            SC2[(wr * 128 + il) * 2 + 1] = nsum[n];
        }
    }
    __syncthreads();
    float rl = 0.f;
    if (t < 128) {
        float ps = SC2[t * 2] + SC2[(128 + t) * 2];
        float ns = SC2[t * 2 + 1] + SC2[(128 + t) * 2 + 1];
        int val = ((int*)(lds + LDS_VAL))[t];
        rl = (val && ps > 0.f && ns > 0.f)
                 ? (0.5f * log1pf(ps) + 0.025f * log1pf(ns)) : 0.f;
    }
#pragma unroll
    for (int off = 32; off; off >>= 1) rl += __shfl_xor(rl, off);
    float* WS = (float*)(lds + LDS_WS);
    __syncthreads();
    if (lane == 0) WS[wv] = rl;
    __syncthreads();
    if (t == 0) atomicAdd(out, (WS[0] + WS[1] + WS[2] + WS[3]) * (1.0f / 8192.0f));
}

extern "C" void kernel_launch(void* const* d_in, const int* in_sizes, int n_in,
                              void* d_out, int out_size, void* d_ws, size_t ws_size,
                              hipStream_t stream) {
    const float* F = (const float*)d_in[0];
    const int* labels = (const int*)d_in[1];
    float* out = (float*)d_out;

    char* w = (char*)d_ws;
    ulonglong2* pl  = (ulonglong2*)w;                    // 131072 B
    unsigned* tneed = (unsigned*)(w + 131072);           // 256 B

    void* args[] = {(void*)&F, (void*)&labels, (void*)&pl, (void*)&tneed, (void*)&out};
    hipLaunchCooperativeKernel((const void*)k_all, dim3(NBLK), dim3(256),
                               args, 0, stream);
}

// Round 10
// 20.989 us; speedup vs baseline: 7.1780x; 7.1780x over previous
//
#include <hip/hip_runtime.h>
#include <math.h>

#define NB 8192
#define ND 64
#define NL 80

typedef __attribute__((ext_vector_type(8))) __bf16 bf16x8;
typedef __attribute__((ext_vector_type(16))) float f32x16;

// LDS layout for k_heavy (40960 B, phase-multiplexed)
#define LDS_AHI 0
#define LDS_ALO 16384
#define LDS_PL  32768
#define LDS_TH  34816
#define LDS_VAL 36864
#define LDS_SCR 37376
#define LDS_ANY 40448
#define LDS_WS  40452

__device__ __forceinline__ unsigned bf16rne(float x) {
    unsigned u = __float_as_uint(x);
    unsigned r = u + 0x7FFFu + ((u >> 16) & 1u);
    return r >> 16;
}
__device__ __forceinline__ float bf16tof(unsigned h) {
    return __uint_as_float(h << 16);
}

// 8 floats -> 8 bf16 hi (uint4) + 8 bf16 lo (uint4)
__device__ __forceinline__ void split8(float4 va, float4 vb, uint4* hi, uint4* lo) {
    float f[8] = {va.x, va.y, va.z, va.w, vb.x, vb.y, vb.z, vb.w};
    unsigned h[8], l[8];
#pragma unroll
    for (int k = 0; k < 8; ++k) {
        h[k] = bf16rne(f[k]);
        l[k] = bf16rne(f[k] - bf16tof(h[k]));
    }
    *hi = make_uint4(h[0] | (h[1] << 16), h[2] | (h[3] << 16),
                     h[4] | (h[5] << 16), h[6] | (h[7] << 16));
    *lo = make_uint4(l[0] | (l[1] << 16), l[2] | (l[3] << 16),
                     l[4] | (l[5] << 16), l[6] | (l[7] << 16));
}

// ---- K1: ballot-pack labels into 80-bit masks; zero tneed/out ----
__global__ __launch_bounds__(256) void k_pack(const int* __restrict__ labels,
        ulonglong2* __restrict__ pl, unsigned* __restrict__ tneed,
        float* __restrict__ out) {
    int gid = blockIdx.x * 256 + threadIdx.x;   // 512 blocks -> 2048 waves
    if (gid < 64) tneed[gid] = 0u;
    if (gid == 0) out[0] = 0.f;
    int lane = threadIdx.x & 63;
    int w = gid >> 6;                           // 0..2047, 4 rows each
    const int* base = labels + (size_t)w * 4 * NL;
#pragma unroll
    for (int r = 0; r < 4; ++r) {
        int v0 = base[r * NL + lane];
        int v1 = (lane < 16) ? base[r * NL + 64 + lane] : 0;
        unsigned long long lo = __ballot(v0 != 0);
        unsigned long long hi = __ballot(v1 != 0);
        if (lane == 0) { pl[w * 4 + r].x = lo; pl[w * 4 + r].y = hi; }
    }
}

// ---- K2: label-only need flags -> tneed, directly ----
// need(row) = (mask != 0  [diagonal => has pos-labeled pair]) && (exists j disjoint).
// Partial per j-slice is exact for the OR-aggregation into the 128-row tile flag.
__global__ __launch_bounds__(256) void k_label(const uint4* __restrict__ pl4,
        unsigned* __restrict__ tneed) {
    __shared__ uint4 PJ[64];
    const int tid = threadIdx.x;
    if (tid < 64) PJ[tid] = pl4[blockIdx.x * 64 + tid];
    __syncthreads();
    const int r0 = blockIdx.y * 1024 + tid * 4;   // 4 consecutive rows
    uint4 mi[4];
    unsigned nm[4] = {0xFFFFFFFFu, 0xFFFFFFFFu, 0xFFFFFFFFu, 0xFFFFFFFFu};
#pragma unroll
    for (int k = 0; k < 4; ++k) mi[k] = pl4[r0 + k];
#pragma unroll 4
    for (int j = 0; j < 64; ++j) {
        uint4 pj = PJ[j];
#pragma unroll
        for (int k = 0; k < 4; ++k) {
            unsigned u = (mi[k].x & pj.x) | (mi[k].y & pj.y) | (mi[k].z & pj.z);
            nm[k] = min(nm[k], u);
        }
    }
    bool need = false;
#pragma unroll
    for (int k = 0; k < 4; ++k) {
        bool pos = (mi[k].x | mi[k].y | mi[k].z) != 0u;
        need = need || (pos && nm[k] == 0u);
    }
    if (need) atomicOr(&tneed[r0 >> 7], 1u);
}

// ---- K3 helpers: fp32 -> bf16 hi/lo on the fly ----
// Stage 128-row A(j) panel, XOR-swizzled (G4: byte ^= (row&7)<<4).
__device__ __forceinline__ void stage_A(char* lds, const float4* __restrict__ F4,
        int j0, int tid) {
#pragma unroll
    for (int t = 0; t < 4; ++t) {
        int idx = tid + t * 256;          // 0..1023
        int row = idx >> 3, c8 = idx & 7;
        float4 v0 = F4[(size_t)(j0 + row) * 16 + c8 * 2];
        float4 v1 = F4[(size_t)(j0 + row) * 16 + c8 * 2 + 1];
        uint4 hi, lo;
        split8(v0, v1, &hi, &lo);
        int dst = row * 128 + ((c8 * 16) ^ ((row & 7) << 4));
        *(uint4*)(lds + LDS_AHI + dst) = hi;
        *(uint4*)(lds + LDS_ALO + dst) = lo;
    }
}

// 64x64 per wave: acc = 3-split product of Fj-panel (LDS) x Fi-panel^T (global fp32).
// C layout (m74/m101): col=lane&31 (i), row=(reg&3)+8*(reg>>2)+4*(lane>>5) (j).
__device__ __forceinline__ void compute_tile(const char* lds,
        const float4* __restrict__ F4, int i0, int wr, int wc, int lane,
        f32x16 acc[2][2]) {
    const int l31 = lane & 31, lhalf = lane >> 5;
    const int swz = (l31 & 7) << 4;
    const int abase = (wr * 64 + l31) * 128;
    const size_t br0 = (size_t)(i0 + wc * 64 + l31) * 16;
    const size_t br1 = br0 + 32 * 16;
#pragma unroll
    for (int ks = 0; ks < 4; ++ks) {
        int off = (ks * 32 + lhalf * 16) ^ swz;
        int ci = ks * 2 + lhalf;
        bf16x8 a0h = *(const bf16x8*)(lds + LDS_AHI + abase + off);
        bf16x8 a1h = *(const bf16x8*)(lds + LDS_AHI + abase + 32 * 128 + off);
        bf16x8 a0l = *(const bf16x8*)(lds + LDS_ALO + abase + off);
        bf16x8 a1l = *(const bf16x8*)(lds + LDS_ALO + abase + 32 * 128 + off);
        uint4 b0hu, b0lu, b1hu, b1lu;
        split8(F4[br0 + ci * 2], F4[br0 + ci * 2 + 1], &b0hu, &b0lu);
        split8(F4[br1 + ci * 2], F4[br1 + ci * 2 + 1], &b1hu, &b1lu);
        bf16x8 b0h = __builtin_bit_cast(bf16x8, b0hu);
        bf16x8 b0l = __builtin_bit_cast(bf16x8, b0lu);
        bf16x8 b1h = __builtin_bit_cast(bf16x8, b1hu);
        bf16x8 b1l = __builtin_bit_cast(bf16x8, b1lu);
        acc[0][0] = __builtin_amdgcn_mfma_f32_32x32x16_bf16(a0h, b0h, acc[0][0], 0, 0, 0);
        acc[0][0] = __builtin_amdgcn_mfma_f32_32x32x16_bf16(a0h, b0l, acc[0][0], 0, 0, 0);
        acc[0][0] = __builtin_amdgcn_mfma_f32_32x32x16_bf16(a0l, b0h, acc[0][0], 0, 0, 0);
        acc[0][1] = __builtin_amdgcn_mfma_f32_32x32x16_bf16(a0h, b1h, acc[0][1], 0, 0, 0);
        acc[0][1] = __builtin_amdgcn_mfma_f32_32x32x16_bf16(a0h, b1l, acc[0][1], 0, 0, 0);
        acc[0][1] = __builtin_amdgcn_mfma_f32_32x32x16_bf16(a0l, b1h, acc[0][1], 0, 0, 0);
        acc[1][0] = __builtin_amdgcn_mfma_f32_32x32x16_bf16(a1h, b0h, acc[1][0], 0, 0, 0);
        acc[1][0] = __builtin_amdgcn_mfma_f32_32x32x16_bf16(a1h, b0l, acc[1][0], 0, 0, 0);
        acc[1][0] = __builtin_amdgcn_mfma_f32_32x32x16_bf16(a1l, b0h, acc[1][0], 0, 0, 0);
        acc[1][1] = __builtin_amdgcn_mfma_f32_32x32x16_bf16(a1h, b1h, acc[1][1], 0, 0, 0);
        acc[1][1] = __builtin_amdgcn_mfma_f32_32x32x16_bf16(a1h, b1l, acc[1][1], 0, 0, 0);
        acc[1][1] = __builtin_amdgcn_mfma_f32_32x32x16_bf16(a1l, b1h, acc[1][1], 0, 0, 0);
    }
}

// ---- K3: gated full sim pipeline, one block per 128-row i-tile ----
__global__ __launch_bounds__(256, 1) void k_heavy(const float* __restrict__ F,
        const ulonglong2* __restrict__ pl, const unsigned* __restrict__ tneed,
        float* __restrict__ out) {
    __shared__ char lds[40960];
    const int b = blockIdx.x;
    if (tneed[b] == 0u) return;           // label-level gate (block-uniform)
    const float4* F4 = (const float4*)F;
    const int t = threadIdx.x;
    const int i0 = b * 128;
    const int lane = t & 63, wv = t >> 6;
    const int wr = wv >> 1, wc = wv & 1;
    const int l31 = lane & 31, lhalf = lane >> 5;

    ulonglong2 pi[2];
    pi[0] = pl[i0 + wc * 64 + l31];
    pi[1] = pl[i0 + wc * 64 + 32 + l31];

    // ---- pass 1: full j-range, stats in regs ----
    float ssq[2] = {0.f, 0.f};
    float mnp[2] = {INFINITY, INFINITY};
    float mxn[2] = {-INFINITY, -INFINITY};
    for (int js = 0; js < 64; ++js) {
        const int j0 = js * 128;
        __syncthreads();
        stage_A(lds, F4, j0, t);
        if (t < 128) *(ulonglong2*)(lds + LDS_PL + t * 16) = pl[j0 + t];
        __syncthreads();
        f32x16 acc[2][2] = {};
        compute_tile(lds, F4, i0, wr, wc, lane, acc);
#pragma unroll
        for (int m = 0; m < 2; ++m) {
#pragma unroll
            for (int reg = 0; reg < 16; ++reg) {
                int jl = wr * 64 + m * 32 + (reg & 3) + 8 * (reg >> 2) + 4 * lhalf;
                ulonglong2 pj = *(const ulonglong2*)(lds + LDS_PL + jl * 16);
#pragma unroll
                for (int n = 0; n < 2; ++n) {
                    float s = acc[m][n][reg];
                    bool pos = (((pi[n].x & pj.x) | (pi[n].y & pj.y)) != 0ull);
                    ssq[n] += s * s;
                    mnp[n] = fminf(mnp[n], pos ? s : INFINITY);
                    mxn[n] = fmaxf(mxn[n], pos ? -INFINITY : s);
                }
            }
        }
    }
#pragma unroll
    for (int n = 0; n < 2; ++n) {
        ssq[n] += __shfl_xor(ssq[n], 32);
        mnp[n] = fminf(mnp[n], __shfl_xor(mnp[n], 32));
        mxn[n] = fmaxf(mxn[n], __shfl_xor(mxn[n], 32));
    }
    float* SC2 = (float*)(lds + LDS_SCR);
    int* ANYV = (int*)(lds + LDS_ANY);
    if (lane < 32) {
#pragma unroll
        for (int n = 0; n < 2; ++n) {
            int il = wc * 64 + n * 32 + lane;
            SC2[(wr * 128 + il) * 3 + 0] = ssq[n];
            SC2[(wr * 128 + il) * 3 + 1] = mnp[n];
            SC2[(wr * 128 + il) * 3 + 2] = mxn[n];
        }
    }
    if (t == 0) *ANYV = 0;
    __syncthreads();
    // ---- per-row thresholds (raw-dot space, verified R0-R7 logic) ----
    if (t < 128) {
        float s2 = SC2[t * 3] + SC2[(128 + t) * 3];
        float mp = fminf(SC2[t * 3 + 1], SC2[(128 + t) * 3 + 1]);
        float mg = fmaxf(SC2[t * 3 + 2], SC2[(128 + t) * 3 + 2]);
        float div = fmaxf(sqrtf(s2), 1e-12f);
        float inv = 1.f / div;
        float eraw = (1.0f - 1e-5f) * div;
        bool hasp = (mp < eraw);
        bool hasn = (mg > -INFINITY);
        float minpos_n = hasp ? mp * inv : INFINITY;
        float maxneg_n = hasn ? mg * inv : -INFINITY;
        float4 th;
        th.x = (minpos_n - 0.1f) * div;   // neg_sel: raw > th.x
        th.y = (maxneg_n + 0.1f) * div;   // pos_sel: raw < th.y
        th.z = eraw;                      // pos_valid: raw < th.z
        th.w = inv;
        *(float4*)(lds + LDS_TH + t * 16) = th;
        ((int*)(lds + LDS_VAL))[t] = (hasp && hasn) ? 1 : 0;
        if (hasp && hasn) *ANYV = 1;
    }
    __syncthreads();
    if (*ANYV == 0) return;               // block-uniform

    // ---- pass 2: mined exp sums ----
    float tn[2], tp[2], te[2], iv[2];
#pragma unroll
    for (int n = 0; n < 2; ++n) {
        int il = wc * 64 + n * 32 + l31;
        float4 th = *(const float4*)(lds + LDS_TH + il * 16);
        tn[n] = th.x; tp[n] = th.y; te[n] = th.z; iv[n] = th.w;
    }
    float psum[2] = {0.f, 0.f}, nsum[2] = {0.f, 0.f};
    for (int js = 0; js < 64; ++js) {
        const int j0 = js * 128;
        __syncthreads();
        stage_A(lds, F4, j0, t);
        if (t < 128) *(ulonglong2*)(lds + LDS_PL + t * 16) = pl[j0 + t];
        __syncthreads();
        f32x16 acc[2][2] = {};
        compute_tile(lds, F4, i0, wr, wc, lane, acc);
#pragma unroll
        for (int m = 0; m < 2; ++m) {
#pragma unroll
            for (int reg = 0; reg < 16; ++reg) {
                int jl = wr * 64 + m * 32 + (reg & 3) + 8 * (reg >> 2) + 4 * lhalf;
                ulonglong2 pj = *(const ulonglong2*)(lds + LDS_PL + jl * 16);
#pragma unroll
                for (int n = 0; n < 2; ++n) {
                    float s = acc[m][n][reg];
                    bool pos = (((pi[n].x & pj.x) | (pi[n].y & pj.y)) != 0ull);
                    float sn = s * iv[n];
                    bool psel = pos && (s < te[n]) && (s < tp[n]);
                    bool nsel = (!pos) && (s > tn[n]);
                    float arg = pos ? fmaf(-2.0f, sn, 0.2f) : fmaf(40.0f, sn, -4.0f);
                    float ev = __expf(arg);
                    psum[n] += psel ? ev : 0.0f;
                    nsum[n] += nsel ? ev : 0.0f;
                }
            }
        }
    }
#pragma unroll
    for (int n = 0; n < 2; ++n) {
        psum[n] += __shfl_xor(psum[n], 32);
        nsum[n] += __shfl_xor(nsum[n], 32);
    }
    __syncthreads();                      // SC2 reuse: threshold reads done
    if (lane < 32) {
#pragma unroll
        for (int n = 0; n < 2; ++n) {
            int il = wc * 64 + n * 32 + lane;
            SC2[(wr * 128 + il) * 2 + 0] = psum[n];
            SC2[(wr * 128 + il) * 2 + 1] = nsum[n];
        }
    }
    __syncthreads();
    // ---- row losses + block sum -> out ----
    float rl = 0.f;
    if (t < 128) {
        float ps = SC2[t * 2] + SC2[(128 + t) * 2];
        float ns = SC2[t * 2 + 1] + SC2[(128 + t) * 2 + 1];
        int val = ((int*)(lds + LDS_VAL))[t];
        rl = (val && ps > 0.f && ns > 0.f)
                 ? (0.5f * log1pf(ps) + 0.025f * log1pf(ns)) : 0.f;
    }
#pragma unroll
    for (int off = 32; off; off >>= 1) rl += __shfl_xor(rl, off);
    float* WS = (float*)(lds + LDS_WS);
    __syncthreads();
    if (lane == 0) WS[wv] = rl;
    __syncthreads();
    if (t == 0) atomicAdd(out, (WS[0] + WS[1] + WS[2] + WS[3]) * (1.0f / 8192.0f));
}

extern "C" void kernel_launch(void* const* d_in, const int* in_sizes, int n_in,
                              void* d_out, int out_size, void* d_ws, size_t ws_size,
                              hipStream_t stream) {
    const float* F = (const float*)d_in[0];
    const int* labels = (const int*)d_in[1];
    float* out = (float*)d_out;

    char* w = (char*)d_ws;
    ulonglong2* pl  = (ulonglong2*)w;                    // 131072 B
    unsigned* tneed = (unsigned*)(w + 131072);           // 256 B

    k_pack<<<512, 256, 0, stream>>>(labels, pl, tneed, out);
    k_label<<<dim3(128, 8), 256, 0, stream>>>((const uint4*)pl, tneed);
    k_heavy<<<64, 256, 0, stream>>>(F, pl, tneed, out);
}